// Round 1
// baseline (7056.062 us; speedup 1.0000x reference)
//
#include <hip/hip_runtime.h>

// out = sum_b A_b @ (X @ W_b) + bias   (algebraic pushdown of the GEMM)
//
// Phase 1: init_out    out[n,:] = bias
// Phase 2: gemm        Y = X @ W'   (W' gathered from shared_weight blocks)
// Phase 3: scatter     per edge e in block b: out[rows[e]] += vals[e] * Y_b[cols[e]]

__global__ __launch_bounds__(256) void init_out_kernel(
    float* __restrict__ out, const float* __restrict__ bias, int nquads)
{
  int i = blockIdx.x * blockDim.x + threadIdx.x;
  if (i >= nquads) return;
  const float4 b = ((const float4*)bias)[i & 31];   // 128 floats = 32 quads per row
  ((float4*)out)[i] = b;
}

// Y[r, blockIdx.x*64 + j] = sum_f X[r,f] * W[(g>>7)*128 + f, g&127],  g = col0 + blockIdx.x*64 + j
// 64x64 tile, 256 threads, 4x4 register tile per thread, K=128 in one shot.
__global__ __launch_bounds__(256) void gemm_kernel(
    const float* __restrict__ X, const float* __restrict__ W,
    float* __restrict__ Y, int n_rows, int col0, int ystride)
{
  __shared__ float Xs[64][128];   // quad-swizzled on (r>>2)&7 to kill bank conflicts
  __shared__ float Ws[128][64];
  const int tid = threadIdx.x;
  const int row0 = blockIdx.y * 64;

  // load X tile (64 rows x 128 cols), float4 per thread, swizzled quad placement
  {
    const int lane = tid & 31;          // quad col 0..31
    const int r = tid >> 5;             // 0..7
#pragma unroll
    for (int i = 0; i < 8; ++i) {
      const int rr = r + i * 8;
      const int gr = row0 + rr;
      float4 v = make_float4(0.f, 0.f, 0.f, 0.f);
      if (gr < n_rows) v = ((const float4*)(X + (size_t)gr * 128))[lane];
      ((float4*)&Xs[rr][0])[lane ^ ((rr >> 2) & 7)] = v;
    }
  }
  // load W tile (128 x 64): Ws[f][j] = W[(b*128+f)*128 + cc0 + j]
  {
    const int gc0 = col0 + blockIdx.x * 64;
    const int b = gc0 >> 7;
    const int cc0 = gc0 & 127;
    const float* Wb = W + (size_t)b * 128 * 128 + cc0;
    const int lane16 = tid & 15;
    const int f = tid >> 4;             // 0..15
#pragma unroll
    for (int i = 0; i < 8; ++i) {
      const int ff = f + i * 16;
      const float4 v = *(const float4*)(Wb + (size_t)ff * 128 + lane16 * 4);
      ((float4*)&Ws[ff][0])[lane16] = v;
    }
  }
  __syncthreads();

  const int tx = tid & 15;
  const int ty = tid >> 4;
  float acc[4][4] = {};
#pragma unroll
  for (int f0 = 0; f0 < 128; f0 += 4) {
    float4 a[4];
#pragma unroll
    for (int i = 0; i < 4; ++i) {
      const int r = ty * 4 + i;
      a[i] = ((const float4*)&Xs[r][0])[(f0 >> 2) ^ ((r >> 2) & 7)];
    }
#pragma unroll
    for (int k = 0; k < 4; ++k) {
      const float4 b = *(const float4*)&Ws[f0 + k][tx * 4];
#pragma unroll
      for (int i = 0; i < 4; ++i) {
        const float av = (&a[i].x)[k];
        acc[i][0] = fmaf(av, b.x, acc[i][0]);
        acc[i][1] = fmaf(av, b.y, acc[i][1]);
        acc[i][2] = fmaf(av, b.z, acc[i][2]);
        acc[i][3] = fmaf(av, b.w, acc[i][3]);
      }
    }
  }
  const int yc = blockIdx.x * 64 + tx * 4;
#pragma unroll
  for (int i = 0; i < 4; ++i) {
    const int gr = row0 + ty * 4 + i;
    if (gr < n_rows) {
      *(float4*)(Y + (size_t)gr * ystride + yc) =
          make_float4(acc[i][0], acc[i][1], acc[i][2], acc[i][3]);
    }
  }
}

// One 32-lane half-wave per edge: lane covers 4 consecutive output features.
__global__ __launch_bounds__(256) void scatter_kernel(
    const int* __restrict__ rows, const int* __restrict__ cols,
    const float* __restrict__ vals, const float* __restrict__ Y,
    int ystride, int yblk, unsigned epb, unsigned ntot,
    float* __restrict__ out)
{
  const unsigned e = blockIdx.x * 8u + (threadIdx.x >> 5);
  if (e >= ntot) return;
  const int lane = threadIdx.x & 31;
  const int row = rows[e];
  const int col = cols[e];
  const float v = vals[e];
  const unsigned b = e / epb;                 // hop index (0 when per-block launch)
  const float4 y = *(const float4*)(Y + (size_t)col * ystride + (size_t)b * yblk + lane * 4);
  float* o = out + (size_t)row * 128 + lane * 4;
  atomicAdd(o + 0, v * y.x);
  atomicAdd(o + 1, v * y.y);
  atomicAdd(o + 2, v * y.z);
  atomicAdd(o + 3, v * y.w);
}

extern "C" void kernel_launch(void* const* d_in, const int* in_sizes, int n_in,
                              void* d_out, int out_size, void* d_ws, size_t ws_size,
                              hipStream_t stream) {
  const float* X    = (const float*)d_in[0];
  const int*   rows = (const int*)d_in[1];
  const int*   cols = (const int*)d_in[2];
  const float* vals = (const float*)d_in[3];
  const float* W    = (const float*)d_in[4];
  const float* bias = (const float*)d_in[5];
  float* out = (float*)d_out;

  const int n = out_size / 128;               // 50000 nodes
  const unsigned ntot = (unsigned)in_sizes[1]; // 4 * 800000 edges, flat
  const unsigned epb = ntot / 4u;             // edges per hop
  float* Y = (float*)d_ws;

  // Phase 1: out = bias
  {
    const int nquads = n * 32;
    init_out_kernel<<<dim3((nquads + 255) / 256), dim3(256), 0, stream>>>(out, bias, nquads);
  }

  const size_t need_fused = (size_t)n * 512 * sizeof(float);
  if (ws_size >= need_fused) {
    // Fused: one GEMM producing Y[n,512], one scatter over all 3.2M edges.
    dim3 g(512 / 64, (n + 63) / 64);
    gemm_kernel<<<g, dim3(256), 0, stream>>>(X, W, Y, n, 0, 512);
    const unsigned nblk = (ntot + 7) / 8;
    scatter_kernel<<<dim3(nblk), dim3(256), 0, stream>>>(
        rows, cols, vals, Y, 512, 128, epb, ntot, out);
  } else {
    // Per-hop fallback: Y[n,128] reused; stream order serializes gemm_b -> scatter_b.
    for (unsigned b = 0; b < 4; ++b) {
      dim3 g(128 / 64, (n + 63) / 64);
      gemm_kernel<<<g, dim3(256), 0, stream>>>(X, W, Y, n, (int)(b * 128), 128);
      const unsigned nblk = (epb + 7) / 8;
      scatter_kernel<<<dim3(nblk), dim3(256), 0, stream>>>(
          rows + (size_t)b * epb, cols + (size_t)b * epb, vals + (size_t)b * epb,
          Y, 128, 0, epb, epb, out);
    }
  }
}

// Round 2
// 2582.855 us; speedup vs baseline: 2.7319x; 2.7319x over previous
//
#include <hip/hip_runtime.h>
#include <hip/hip_bf16.h>
#include <type_traits>

// out = sum_b A_b @ (X @ W_b) + bias
// Phase 1: Y = X @ W'          (fused [n,512], hop-major columns)
// Phase 2: CSR build on rows   (hist -> scan -> fill perm)
// Phase 3: gather              one wave per output row, no float atomics

// ---------------- GEMM: Y[r, 64*bx + j] ----------------
template <typename YT>
__global__ __launch_bounds__(256) void gemm_kernel(
    const float* __restrict__ X, const float* __restrict__ W,
    YT* __restrict__ Y, int n_rows, int col0, int ystride)
{
  __shared__ float Xs[64][128];
  __shared__ float Ws[128][64];
  const int tid = threadIdx.x;
  const int row0 = blockIdx.y * 64;

  {
    const int lane = tid & 31;
    const int r = tid >> 5;
#pragma unroll
    for (int i = 0; i < 8; ++i) {
      const int rr = r + i * 8;
      const int gr = row0 + rr;
      float4 v = make_float4(0.f, 0.f, 0.f, 0.f);
      if (gr < n_rows) v = ((const float4*)(X + (size_t)gr * 128))[lane];
      ((float4*)&Xs[rr][0])[lane ^ ((rr >> 2) & 7)] = v;
    }
  }
  {
    const int gc0 = col0 + blockIdx.x * 64;
    const int b = gc0 >> 7;
    const int cc0 = gc0 & 127;
    const float* Wb = W + (size_t)b * 128 * 128 + cc0;
    const int lane16 = tid & 15;
    const int f = tid >> 4;
#pragma unroll
    for (int i = 0; i < 8; ++i) {
      const int ff = f + i * 16;
      const float4 v = *(const float4*)(Wb + (size_t)ff * 128 + lane16 * 4);
      ((float4*)&Ws[ff][0])[lane16] = v;
    }
  }
  __syncthreads();

  const int tx = tid & 15;
  const int ty = tid >> 4;
  float acc[4][4] = {};
#pragma unroll
  for (int f0 = 0; f0 < 128; f0 += 4) {
    float4 a[4];
#pragma unroll
    for (int i = 0; i < 4; ++i) {
      const int r = ty * 4 + i;
      a[i] = ((const float4*)&Xs[r][0])[(f0 >> 2) ^ ((r >> 2) & 7)];
    }
#pragma unroll
    for (int k = 0; k < 4; ++k) {
      const float4 b = *(const float4*)&Ws[f0 + k][tx * 4];
#pragma unroll
      for (int i = 0; i < 4; ++i) {
        const float av = (&a[i].x)[k];
        acc[i][0] = fmaf(av, b.x, acc[i][0]);
        acc[i][1] = fmaf(av, b.y, acc[i][1]);
        acc[i][2] = fmaf(av, b.z, acc[i][2]);
        acc[i][3] = fmaf(av, b.w, acc[i][3]);
      }
    }
  }
  const int yc = blockIdx.x * 64 + tx * 4;
#pragma unroll
  for (int i = 0; i < 4; ++i) {
    const int gr = row0 + ty * 4 + i;
    if (gr >= n_rows) continue;
    if constexpr (std::is_same<YT, float>::value) {
      *(float4*)(Y + (size_t)gr * ystride + yc) =
          make_float4(acc[i][0], acc[i][1], acc[i][2], acc[i][3]);
    } else {
      union { ushort4 u; __hip_bfloat16 h[4]; } p;
      p.h[0] = __float2bfloat16(acc[i][0]);
      p.h[1] = __float2bfloat16(acc[i][1]);
      p.h[2] = __float2bfloat16(acc[i][2]);
      p.h[3] = __float2bfloat16(acc[i][3]);
      *(ushort4*)(Y + (size_t)gr * ystride + yc) = p.u;
    }
  }
}

// ---------------- CSR build ----------------
__global__ __launch_bounds__(256) void hist_kernel(
    const int* __restrict__ rows, int* __restrict__ counts, unsigned ntot)
{
  const unsigned e = blockIdx.x * 256u + threadIdx.x;
  if (e < ntot) atomicAdd(&counts[rows[e]], 1);
}

__global__ __launch_bounds__(1024) void scan_kernel(
    const int* __restrict__ counts, int* __restrict__ row_start,
    int* __restrict__ cursor, int n, int ntot)
{
  __shared__ int partial[1024];
  const int tid = threadIdx.x;
  const int per = (n + 1023) / 1024;
  const int s = tid * per;
  const int eidx = (s + per < n) ? (s + per) : n;
  int sum = 0;
  for (int i = s; i < eidx; ++i) sum += counts[i];
  partial[tid] = sum;
  __syncthreads();
  for (int off = 1; off < 1024; off <<= 1) {
    const int add = (tid >= off) ? partial[tid - off] : 0;
    __syncthreads();
    partial[tid] += add;
    __syncthreads();
  }
  int base = (tid == 0) ? 0 : partial[tid - 1];
  for (int i = s; i < eidx; ++i) {
    row_start[i] = base;
    cursor[i] = base;
    base += counts[i];
  }
  if (tid == 0) row_start[n] = ntot;
}

__global__ __launch_bounds__(256) void fill_kernel(
    const int* __restrict__ rows, int* __restrict__ cursor,
    int* __restrict__ perm, unsigned ntot)
{
  const unsigned e = blockIdx.x * 256u + threadIdx.x;
  if (e < ntot) {
    const int r = rows[e];
    const int pos = atomicAdd(&cursor[r], 1);
    perm[pos] = (int)e;
  }
}

// ---------------- gather: one wave per output row ----------------
template <typename YT>
__global__ __launch_bounds__(256) void gather_kernel(
    const int* __restrict__ row_start, const int* __restrict__ perm,
    const int* __restrict__ cols, const float* __restrict__ vals,
    const YT* __restrict__ Y, const float* __restrict__ bias,
    float* __restrict__ out, int n, unsigned epb)
{
  const int wid = (int)((blockIdx.x * 256u + threadIdx.x) >> 6);
  if (wid >= n) return;
  const int lane = threadIdx.x & 63;
  const int js = row_start[wid];
  const int je = row_start[wid + 1];
  float ax = 0.f, ay = 0.f;

  auto ld = [&](unsigned e) -> float2 {
    const unsigned col = (unsigned)cols[e];
    const unsigned b = (e >= 2u * epb) ? ((e >= 3u * epb) ? 3u : 2u)
                                       : ((e >= epb) ? 1u : 0u);
    const YT* yp = Y + (size_t)col * 512 + b * 128 + lane * 2;
    if constexpr (std::is_same<YT, float>::value) {
      return *(const float2*)yp;
    } else {
      const __hip_bfloat162 h = *(const __hip_bfloat162*)yp;
      return make_float2(__low2float(h), __high2float(h));
    }
  };

  int j = js;
  for (; j + 1 < je; j += 2) {
    const unsigned e0 = (unsigned)perm[j];
    const unsigned e1 = (unsigned)perm[j + 1];
    const float v0 = vals[e0];
    const float v1 = vals[e1];
    const float2 y0 = ld(e0);
    const float2 y1 = ld(e1);
    ax = fmaf(v0, y0.x, ax); ay = fmaf(v0, y0.y, ay);
    ax = fmaf(v1, y1.x, ax); ay = fmaf(v1, y1.y, ay);
  }
  if (j < je) {
    const unsigned e0 = (unsigned)perm[j];
    const float v0 = vals[e0];
    const float2 y0 = ld(e0);
    ax = fmaf(v0, y0.x, ax); ay = fmaf(v0, y0.y, ay);
  }
  const float2 bb = *(const float2*)(bias + lane * 2);
  *(float2*)(out + (size_t)wid * 128 + lane * 2) = make_float2(ax + bb.x, ay + bb.y);
}

// ---------------- fallback (round-1 path) ----------------
__global__ __launch_bounds__(256) void init_out_kernel(
    float* __restrict__ out, const float* __restrict__ bias, int nquads)
{
  int i = blockIdx.x * blockDim.x + threadIdx.x;
  if (i >= nquads) return;
  const float4 b = ((const float4*)bias)[i & 31];
  ((float4*)out)[i] = b;
}

__global__ __launch_bounds__(256) void scatter_kernel(
    const int* __restrict__ rows, const int* __restrict__ cols,
    const float* __restrict__ vals, const float* __restrict__ Y,
    int ystride, int yblk, unsigned epb, unsigned ntot,
    float* __restrict__ out)
{
  const unsigned e = blockIdx.x * 8u + (threadIdx.x >> 5);
  if (e >= ntot) return;
  const int lane = threadIdx.x & 31;
  const int row = rows[e];
  const int col = cols[e];
  const float v = vals[e];
  const unsigned b = e / epb;
  const float4 y = *(const float4*)(Y + (size_t)col * ystride + (size_t)b * yblk + lane * 4);
  float* o = out + (size_t)row * 128 + lane * 4;
  atomicAdd(o + 0, v * y.x);
  atomicAdd(o + 1, v * y.y);
  atomicAdd(o + 2, v * y.z);
  atomicAdd(o + 3, v * y.w);
}

extern "C" void kernel_launch(void* const* d_in, const int* in_sizes, int n_in,
                              void* d_out, int out_size, void* d_ws, size_t ws_size,
                              hipStream_t stream) {
  const float* X    = (const float*)d_in[0];
  const int*   rows = (const int*)d_in[1];
  const int*   cols = (const int*)d_in[2];
  const float* vals = (const float*)d_in[3];
  const float* W    = (const float*)d_in[4];
  const float* bias = (const float*)d_in[5];
  float* out = (float*)d_out;

  const int n = out_size / 128;                 // 50000
  const unsigned ntot = (unsigned)in_sizes[1];  // 3.2M
  const unsigned epb = ntot / 4u;

  auto align = [](size_t x) { return (x + 255) & ~(size_t)255; };
  const size_t sz_counts = align((size_t)n * 4);
  const size_t sz_start  = align((size_t)(n + 1) * 4);
  const size_t sz_cursor = align((size_t)n * 4);
  const size_t sz_perm   = align((size_t)ntot * 4);
  const size_t csr_bytes = sz_counts + sz_start + sz_cursor + sz_perm;
  const size_t sz_y_f32  = align((size_t)n * 512 * 4);
  const size_t sz_y_bf16 = align((size_t)n * 512 * 2);

  char* ws = (char*)d_ws;
  int* counts    = (int*)(ws);
  int* row_start = (int*)(ws + sz_counts);
  int* cursor    = (int*)(ws + sz_counts + sz_start);
  int* perm      = (int*)(ws + sz_counts + sz_start + sz_cursor);
  char* ybase    = ws + csr_bytes;

  const bool fit_f32  = ws_size >= csr_bytes + sz_y_f32;
  const bool fit_bf16 = ws_size >= csr_bytes + sz_y_bf16;

  if (fit_f32 || fit_bf16) {
    // CSR build
    hipMemsetAsync(counts, 0, (size_t)n * 4, stream);
    const unsigned eblk = (ntot + 255) / 256;
    hist_kernel<<<dim3(eblk), dim3(256), 0, stream>>>(rows, counts, ntot);
    scan_kernel<<<dim3(1), dim3(1024), 0, stream>>>(counts, row_start, cursor, n, (int)ntot);
    fill_kernel<<<dim3(eblk), dim3(256), 0, stream>>>(rows, cursor, perm, ntot);
    // GEMM + gather
    dim3 g(512 / 64, (n + 63) / 64);
    const unsigned gblk = (unsigned)((n + 3) / 4);   // 4 waves per block
    if (fit_f32) {
      float* Y = (float*)ybase;
      gemm_kernel<float><<<g, dim3(256), 0, stream>>>(X, W, Y, n, 0, 512);
      gather_kernel<float><<<dim3(gblk), dim3(256), 0, stream>>>(
          row_start, perm, cols, vals, Y, bias, out, n, epb);
    } else {
      __hip_bfloat16* Y = (__hip_bfloat16*)ybase;
      gemm_kernel<__hip_bfloat16><<<g, dim3(256), 0, stream>>>(X, W, Y, n, 0, 512);
      gather_kernel<__hip_bfloat16><<<dim3(gblk), dim3(256), 0, stream>>>(
          row_start, perm, cols, vals, Y, bias, out, n, epb);
    }
    return;
  }

  // Fallback: round-1 atomic path
  {
    const int nquads = n * 32;
    init_out_kernel<<<dim3((nquads + 255) / 256), dim3(256), 0, stream>>>(out, bias, nquads);
    float* Y = (float*)d_ws;
    const size_t need_fused = (size_t)n * 512 * sizeof(float);
    if (ws_size >= need_fused) {
      dim3 g(512 / 64, (n + 63) / 64);
      gemm_kernel<float><<<g, dim3(256), 0, stream>>>(X, W, Y, n, 0, 512);
      const unsigned nblk = (ntot + 7) / 8;
      scatter_kernel<<<dim3(nblk), dim3(256), 0, stream>>>(
          rows, cols, vals, Y, 512, 128, epb, ntot, out);
    } else {
      for (unsigned b = 0; b < 4; ++b) {
        dim3 g(128 / 64, (n + 63) / 64);
        gemm_kernel<float><<<g, dim3(256), 0, stream>>>(X, W, Y, n, (int)(b * 128), 128);
        const unsigned nblk = (epb + 7) / 8;
        scatter_kernel<<<dim3(nblk), dim3(256), 0, stream>>>(
            rows + (size_t)b * epb, cols + (size_t)b * epb, vals + (size_t)b * epb,
            Y, 128, 0, epb, epb, out);
      }
    }
  }
}

// Round 3
// 697.152 us; speedup vs baseline: 10.1213x; 3.7049x over previous
//
#include <hip/hip_runtime.h>
#include <hip/hip_bf16.h>
#include <type_traits>

// out = sum_b A_b @ (X @ W_b) + bias
// Phase 1: CSR build on rows (hist -> scan -> fill packed {yoff, val})
// Phase 2: Y = X @ W'  (fp32 compute, bf16 store; [n,512] hop-major cols)
// Phase 3: gather: one wave per output row, sequential packed-edge reads,
//          coalesced 256B Y reads, zero float atomics.

// ---------------- GEMM ----------------
template <typename YT>
__global__ __launch_bounds__(256, 2) void gemm_kernel(
    const float* __restrict__ X, const float* __restrict__ W,
    YT* __restrict__ Y, int n_rows, int col0, int ystride)
{
  __shared__ float Xs[64][128];   // quad-swizzled on (r>>2)&7
  __shared__ float Ws[128][64];
  const int tid = threadIdx.x;
  const int row0 = blockIdx.y * 64;

  {
    const int lane = tid & 31;
    const int r = tid >> 5;
#pragma unroll
    for (int i = 0; i < 8; ++i) {
      const int rr = r + i * 8;
      const int gr = row0 + rr;
      float4 v = make_float4(0.f, 0.f, 0.f, 0.f);
      if (gr < n_rows) v = ((const float4*)(X + (size_t)gr * 128))[lane];
      ((float4*)&Xs[rr][0])[lane ^ ((rr >> 2) & 7)] = v;
    }
  }
  {
    const int gc0 = col0 + blockIdx.x * 64;
    const int b = gc0 >> 7;
    const int cc0 = gc0 & 127;
    const float* Wb = W + (size_t)b * 128 * 128 + cc0;
    const int lane16 = tid & 15;
    const int f = tid >> 4;
#pragma unroll
    for (int i = 0; i < 8; ++i) {
      const int ff = f + i * 16;
      const float4 v = *(const float4*)(Wb + (size_t)ff * 128 + lane16 * 4);
      ((float4*)&Ws[ff][0])[lane16] = v;
    }
  }
  __syncthreads();

  const int tx = tid & 15;
  const int ty = tid >> 4;
  float acc[4][4] = {};
#pragma unroll 2
  for (int f0 = 0; f0 < 128; f0 += 4) {
    float4 a[4];
#pragma unroll
    for (int i = 0; i < 4; ++i) {
      const int r = ty * 4 + i;
      a[i] = ((const float4*)&Xs[r][0])[(f0 >> 2) ^ ((r >> 2) & 7)];
    }
#pragma unroll
    for (int k = 0; k < 4; ++k) {
      const float4 b = *(const float4*)&Ws[f0 + k][tx * 4];
#pragma unroll
      for (int i = 0; i < 4; ++i) {
        const float av = (&a[i].x)[k];
        acc[i][0] = fmaf(av, b.x, acc[i][0]);
        acc[i][1] = fmaf(av, b.y, acc[i][1]);
        acc[i][2] = fmaf(av, b.z, acc[i][2]);
        acc[i][3] = fmaf(av, b.w, acc[i][3]);
      }
    }
  }
  const int yc = blockIdx.x * 64 + tx * 4;
#pragma unroll
  for (int i = 0; i < 4; ++i) {
    const int gr = row0 + ty * 4 + i;
    if (gr >= n_rows) continue;
    if constexpr (std::is_same<YT, float>::value) {
      *(float4*)(Y + (size_t)gr * ystride + yc) =
          make_float4(acc[i][0], acc[i][1], acc[i][2], acc[i][3]);
    } else {
      union { ushort4 u; __hip_bfloat16 h[4]; } p;
      p.h[0] = __float2bfloat16(acc[i][0]);
      p.h[1] = __float2bfloat16(acc[i][1]);
      p.h[2] = __float2bfloat16(acc[i][2]);
      p.h[3] = __float2bfloat16(acc[i][3]);
      *(ushort4*)(Y + (size_t)gr * ystride + yc) = p.u;
    }
  }
}

// ---------------- CSR build ----------------
__global__ __launch_bounds__(256) void hist_kernel(
    const int* __restrict__ rows, int* __restrict__ counts, unsigned ntot)
{
  const unsigned e = blockIdx.x * 256u + threadIdx.x;
  if (e < ntot) atomicAdd(&counts[rows[e]], 1);
}

__global__ __launch_bounds__(1024) void scan_kernel(
    const int* __restrict__ counts, int* __restrict__ row_start,
    int* __restrict__ cursor, int n, int ntot)
{
  __shared__ int partial[1024];
  const int tid = threadIdx.x;
  const int per = (n + 1023) / 1024;
  const int s = tid * per;
  const int eidx = (s + per < n) ? (s + per) : n;
  int sum = 0;
  for (int i = s; i < eidx; ++i) sum += counts[i];
  partial[tid] = sum;
  __syncthreads();
  for (int off = 1; off < 1024; off <<= 1) {
    const int add = (tid >= off) ? partial[tid - off] : 0;
    __syncthreads();
    partial[tid] += add;
    __syncthreads();
  }
  int base = (tid == 0) ? 0 : partial[tid - 1];
  for (int i = s; i < eidx; ++i) {
    row_start[i] = base;
    cursor[i] = base;
    base += counts[i];
  }
  if (tid == 0) row_start[n] = ntot;
}

// Packs per-edge payload at its CSR slot: {Y element offset, val bits}.
__global__ __launch_bounds__(256) void fill_kernel(
    const int* __restrict__ rows, const int* __restrict__ cols,
    const float* __restrict__ vals, int* __restrict__ cursor,
    uint2* __restrict__ ep, unsigned epb, unsigned ntot)
{
  const unsigned e = blockIdx.x * 256u + threadIdx.x;
  if (e >= ntot) return;
  const int r = rows[e];
  const unsigned b = (e >= 2u * epb) ? ((e >= 3u * epb) ? 3u : 2u)
                                     : ((e >= epb) ? 1u : 0u);
  const unsigned yoff = (unsigned)cols[e] * 512u + b * 128u;
  const float v = vals[e];
  const int pos = atomicAdd(&cursor[r], 1);
  ep[pos] = make_uint2(yoff, __float_as_uint(v));
}

// ---------------- gather: one wave per output row ----------------
template <typename YT>
__global__ __launch_bounds__(256) void gather_kernel(
    const int* __restrict__ row_start, const uint2* __restrict__ ep,
    const YT* __restrict__ Y, const float* __restrict__ bias,
    float* __restrict__ out, int n)
{
  const int wid = (int)((blockIdx.x * 256u + threadIdx.x) >> 6);
  if (wid >= n) return;
  const int lane = threadIdx.x & 63;
  const int js = row_start[wid];
  const int je = row_start[wid + 1];
  float ax = 0.f, ay = 0.f;

  auto ld = [&](uint2 p) -> float2 {
    const YT* yp = Y + (size_t)p.x + lane * 2;
    float2 y;
    if constexpr (std::is_same<YT, float>::value) {
      y = *(const float2*)yp;
    } else {
      const __hip_bfloat162 h = *(const __hip_bfloat162*)yp;
      y = make_float2(__low2float(h), __high2float(h));
    }
    const float v = __uint_as_float(p.y);
    return make_float2(v * y.x, v * y.y);
  };

  int j = js;
  for (; j + 3 < je; j += 4) {
    const uint2 p0 = ep[j], p1 = ep[j + 1], p2 = ep[j + 2], p3 = ep[j + 3];
    const float2 t0 = ld(p0), t1 = ld(p1), t2 = ld(p2), t3 = ld(p3);
    ax += (t0.x + t1.x) + (t2.x + t3.x);
    ay += (t0.y + t1.y) + (t2.y + t3.y);
  }
  for (; j < je; ++j) {
    const float2 t = ld(ep[j]);
    ax += t.x; ay += t.y;
  }
  const float2 bb = *(const float2*)(bias + lane * 2);
  *(float2*)(out + (size_t)wid * 128 + lane * 2) = make_float2(ax + bb.x, ay + bb.y);
}

// ---------------- fallback (atomic path) ----------------
__global__ __launch_bounds__(256) void init_out_kernel(
    float* __restrict__ out, const float* __restrict__ bias, int nquads)
{
  int i = blockIdx.x * blockDim.x + threadIdx.x;
  if (i >= nquads) return;
  const float4 b = ((const float4*)bias)[i & 31];
  ((float4*)out)[i] = b;
}

__global__ __launch_bounds__(256) void scatter_kernel(
    const int* __restrict__ rows, const int* __restrict__ cols,
    const float* __restrict__ vals, const float* __restrict__ Y,
    int ystride, int yblk, unsigned epb, unsigned ntot,
    float* __restrict__ out)
{
  const unsigned e = blockIdx.x * 8u + (threadIdx.x >> 5);
  if (e >= ntot) return;
  const int lane = threadIdx.x & 31;
  const int row = rows[e];
  const int col = cols[e];
  const float v = vals[e];
  const unsigned b = e / epb;
  const float4 y = *(const float4*)(Y + (size_t)col * ystride + (size_t)b * yblk + lane * 4);
  float* o = out + (size_t)row * 128 + lane * 4;
  atomicAdd(o + 0, v * y.x);
  atomicAdd(o + 1, v * y.y);
  atomicAdd(o + 2, v * y.z);
  atomicAdd(o + 3, v * y.w);
}

extern "C" void kernel_launch(void* const* d_in, const int* in_sizes, int n_in,
                              void* d_out, int out_size, void* d_ws, size_t ws_size,
                              hipStream_t stream) {
  const float* X    = (const float*)d_in[0];
  const int*   rows = (const int*)d_in[1];
  const int*   cols = (const int*)d_in[2];
  const float* vals = (const float*)d_in[3];
  const float* W    = (const float*)d_in[4];
  const float* bias = (const float*)d_in[5];
  float* out = (float*)d_out;

  const int n = out_size / 128;                 // 50000
  const unsigned ntot = (unsigned)in_sizes[1];  // 3.2M
  const unsigned epb = ntot / 4u;

  auto align = [](size_t x) { return (x + 255) & ~(size_t)255; };
  const size_t sz_counts = align((size_t)n * 4);
  const size_t sz_start  = align((size_t)(n + 1) * 4);
  const size_t sz_cursor = align((size_t)n * 4);
  const size_t sz_ep     = align((size_t)ntot * 8);
  const size_t csr_bytes = sz_counts + sz_start + sz_cursor + sz_ep;
  const size_t sz_y_bf16 = align((size_t)n * 512 * 2);
  const size_t sz_y_f32  = align((size_t)n * 512 * 4);

  char* ws = (char*)d_ws;
  int*   counts    = (int*)(ws);
  int*   row_start = (int*)(ws + sz_counts);
  int*   cursor    = (int*)(ws + sz_counts + sz_start);
  uint2* ep        = (uint2*)(ws + sz_counts + sz_start + sz_cursor);
  char*  ybase     = ws + csr_bytes;

  if (ws_size >= csr_bytes + sz_y_bf16) {
    // CSR build
    hipMemsetAsync(counts, 0, (size_t)n * 4, stream);
    const unsigned eblk = (ntot + 255) / 256;
    hist_kernel<<<dim3(eblk), dim3(256), 0, stream>>>(rows, counts, ntot);
    scan_kernel<<<dim3(1), dim3(1024), 0, stream>>>(counts, row_start, cursor, n, (int)ntot);
    fill_kernel<<<dim3(eblk), dim3(256), 0, stream>>>(rows, cols, vals, cursor, ep, epb, ntot);
    // GEMM (fp32 compute, bf16 store) + gather
    __hip_bfloat16* Y = (__hip_bfloat16*)ybase;
    dim3 g(512 / 64, (n + 63) / 64);
    gemm_kernel<__hip_bfloat16><<<g, dim3(256), 0, stream>>>(X, W, Y, n, 0, 512);
    const unsigned gblk = (unsigned)((n + 3) / 4);
    gather_kernel<__hip_bfloat16><<<dim3(gblk), dim3(256), 0, stream>>>(
        row_start, ep, Y, bias, out, n);
    return;
  }

  // Fallback: atomic path
  {
    const int nquads = n * 32;
    init_out_kernel<<<dim3((nquads + 255) / 256), dim3(256), 0, stream>>>(out, bias, nquads);
    float* Y = (float*)d_ws;
    const size_t need_fused = (size_t)n * 512 * sizeof(float);
    if (ws_size >= need_fused) {
      dim3 g(512 / 64, (n + 63) / 64);
      gemm_kernel<float><<<g, dim3(256), 0, stream>>>(X, W, Y, n, 0, 512);
      const unsigned nblk = (ntot + 7) / 8;
      scatter_kernel<<<dim3(nblk), dim3(256), 0, stream>>>(
          rows, cols, vals, Y, 512, 128, epb, ntot, out);
    } else {
      for (unsigned b = 0; b < 4; ++b) {
        dim3 g(128 / 64, (n + 63) / 64);
        gemm_kernel<float><<<g, dim3(256), 0, stream>>>(X, W, Y, n, (int)(b * 128), 128);
        const unsigned nblk = (epb + 7) / 8;
        scatter_kernel<<<dim3(nblk), dim3(256), 0, stream>>>(
            rows + (size_t)b * epb, cols + (size_t)b * epb, vals + (size_t)b * epb,
            Y, 128, 0, epb, epb, out);
      }
    }
  }
}